// Round 8
// baseline (65.723 us; speedup 1.0000x reference)
//
#include <hip/hip_runtime.h>

#define N2 (768 * 768)
#define NH 32
#define PPC 64       // pairs per chunk
#define CHUNKS 4     // chunks per block; 2304 blocks * 256 pairs = N2 exactly
#define TPB 256

// out[h,p] = b[h]*S0[p] + sum_k W[h][k]*S[k][p], S0 = sum_e c_e,
// S[k] = sum_e c_e * ea[node_e][k] over pair p's entry segment.
// pair_idx is sorted ascending over the valid prefix; padding has coeff==0,
// so key(e) = (coeff==0 ? INT_MAX : pair[e]) is globally sorted. Per-block
// batched lower_bound gives chunk entry ranges (padding excluded entirely).
// Boundary pass (coalesced pair reads) fills ps/pe; 4 threads walk each pair
// from global (L1/L3-warm), shfl_xor-merge, stage 5-float summary in LDS,
// then all 256 threads expand to 32 channels with 256B/wave coalesced NT
// stores. Every output element written exactly once; missing pairs get
// ps=pe=0 -> exact zeros, matching segment_sum.
__global__ __launch_bounds__(256) void fused_kernel(
    const int* __restrict__ pair, const int* __restrict__ node,
    const float* __restrict__ coeff, const float* __restrict__ ea,
    const float* __restrict__ W, const float* __restrict__ b,
    float* __restrict__ out, int M)
{
    __shared__ int ps[PPC], pe[PPC];
    __shared__ float sum[5][PPC];
    __shared__ int sBnd[CHUNKS + 1];
    __shared__ float sW[NH * 4];
    __shared__ float sBias[NH];

    const int t = threadIdx.x;
    const int pbase = blockIdx.x * (PPC * CHUNKS);

    if (t < NH * 4) sW[t] = W[t];
    if (t < NH) sBias[t] = b[t];

    if (t <= CHUNKS) {   // 5 concurrent lower_bounds, ~24 probes each
        int target = pbase + t * PPC;
        int lo = 0, hi = M;
        while (lo < hi) {
            int mid = (lo + hi) >> 1;
            int key = (coeff[mid] == 0.f) ? 0x7fffffff : pair[mid];
            if (key < target) lo = mid + 1; else hi = mid;
        }
        sBnd[t] = lo;
    }
    __syncthreads();

    for (int c = 0; c < CHUNKS; ++c) {
        if (t < PPC) { ps[t] = 0; pe[t] = 0; }
        __syncthreads();
        const int p0 = pbase + c * PPC;
        const int s0 = sBnd[c], s1 = sBnd[c + 1];
        const int cnt = s1 - s0;

        // run-boundary detection, coalesced over the chunk's entry range
        for (int i = t; i < cnt; i += TPB) {
            int e = s0 + i;
            int pp = pair[e];
            if (i == 0 || pair[e - 1] != pp) ps[pp - p0] = i;
            if (i == cnt - 1 || pair[e + 1] != pp) pe[pp - p0] = i + 1;
        }
        __syncthreads();

        // 4 threads per pair walk the segment from global
        {
            const int q = t >> 2, sub = t & 3;
            float a0 = 0.f, a1 = 0.f, a2 = 0.f, a3 = 0.f, a4 = 0.f;
            const int ke = s0 + pe[q];
            for (int k = s0 + ps[q] + sub; k < ke; k += 4) {
                float cc = coeff[k];
                int nd = node[k];
                const float4 v = *reinterpret_cast<const float4*>(ea + nd * 4);
                a0 += cc;
                a1 += cc * v.x; a2 += cc * v.y; a3 += cc * v.z; a4 += cc * v.w;
            }
#pragma unroll
            for (int d = 1; d < 4; d <<= 1) {
                a0 += __shfl_xor(a0, d);
                a1 += __shfl_xor(a1, d);
                a2 += __shfl_xor(a2, d);
                a3 += __shfl_xor(a3, d);
                a4 += __shfl_xor(a4, d);
            }
            if (sub == 0) {
                sum[0][q] = a0; sum[1][q] = a1; sum[2][q] = a2;
                sum[3][q] = a3; sum[4][q] = a4;
            }
        }
        __syncthreads();

        // fused expansion: thread t -> pair (t&63), channels (t>>6)*8..+8
        {
            const int q2 = t & 63;
            const int cb = t >> 6;
            const float a0 = sum[0][q2], a1 = sum[1][q2], a2 = sum[2][q2],
                        a3 = sum[3][q2], a4 = sum[4][q2];
            const size_t op = (size_t)(p0 + q2);
#pragma unroll
            for (int j = 0; j < 8; ++j) {
                const int h = cb * 8 + j;
                float val = sBias[h] * a0 + sW[h * 4 + 0] * a1 + sW[h * 4 + 1] * a2
                          + sW[h * 4 + 2] * a3 + sW[h * 4 + 3] * a4;
                __builtin_nontemporal_store(val, out + (size_t)h * N2 + op);
            }
        }
        __syncthreads();   // sum/ps/pe reused next chunk
    }
}

extern "C" void kernel_launch(void* const* d_in, const int* in_sizes, int n_in,
                              void* d_out, int out_size, void* d_ws, size_t ws_size,
                              hipStream_t stream) {
    // inputs: 0=x 1=edge_attr 2=W 3=b 4=edge_idx 5=pair_idx 6=node_idx 7=coeff 8=num_nodes
    const float* ea    = (const float*)d_in[1];
    const float* W     = (const float*)d_in[2];
    const float* b     = (const float*)d_in[3];
    const int*   pair  = (const int*)d_in[5];
    const int*   node  = (const int*)d_in[6];
    const float* coeff = (const float*)d_in[7];
    float* out = (float*)d_out;
    int M = in_sizes[5];

    fused_kernel<<<N2 / (PPC * CHUNKS), TPB, 0, stream>>>(
        pair, node, coeff, ea, W, b, out, M);
}